// Round 6
// baseline (18.082 us; speedup 1.0000x reference)
//
#include <hip/hip_runtime.h>

namespace {
constexpr int Bc  = 16;
constexpr int Nc  = 96;
constexpr int KRc = 16;
constexpr int KAc = 8;
constexpr int NOUT = KRc + KAc;        // 24
constexpr int NNb  = Nc - 1;           // 95 neighbors per atom
constexpr float RCRf = 5.2f;
constexpr float RCAf = 3.5f;
constexpr float L2E  = 1.4426950408889634f;
}

typedef float v2f __attribute__((ext_vector_type(2)));
typedef float v4f __attribute__((ext_vector_type(4)));

__device__ __forceinline__ v2f sp(float x) { return (v2f){x, x}; }
__device__ __forceinline__ v2f pfma(v2f a, v2f b, v2f c) {
    return __builtin_elementwise_fma(a, b, c);
}
__device__ __forceinline__ v2f pmax(v2f a, v2f b) {
    return __builtin_elementwise_max(a, b);
}
__device__ __forceinline__ v2f pexp2(v2f x) {
    return (v2f){__builtin_amdgcn_exp2f(x.x), __builtin_amdgcn_exp2f(x.y)};
}
__device__ __forceinline__ v2f pcosr(v2f rev) {   // cos(2*pi*rev), rev >= 0
    return (v2f){__builtin_amdgcn_cosf(__builtin_amdgcn_fractf(rev.x)),
                 __builtin_amdgcn_cosf(__builtin_amdgcn_fractf(rev.y))};
}
__device__ __forceinline__ v2f psqrt(v2f x) {
    return (v2f){__builtin_amdgcn_sqrtf(x.x), __builtin_amdgcn_sqrtf(x.y)};
}
__device__ __forceinline__ float cos_rev(float rev) {
    return __builtin_amdgcn_cosf(__builtin_amdgcn_fractf(rev));
}

// 256 threads/block, 6 blocks/CU (grid 1536 == co-resident slots).
// Angular work item = packed-pair slot (j, rr): x-lane = pair (j, j+rr),
// y-lane = pair (j, j+rr+1), indices mod 95, rr odd in 1..47 (rr==48 y-slot
// masked). 95 cols x 24 round-slots = 2280 items -> 9 iters x 256 threads.
__global__ __launch_bounds__(256, 6) void ani_feat_kernel(
    const float* __restrict__ coords,      // (B,N,3)
    const int*   __restrict__ atom_types,  // (N,)
    const float* __restrict__ EtaR,        // (T,KR)
    const float* __restrict__ ShfR,        // (T,KR)
    const float* __restrict__ Zeta,        // (T,KA)
    const float* __restrict__ EtaA,        // (T,KA)
    float* __restrict__ out)               // (B,N,24)
{
    const int bi = blockIdx.x;             // b*N + i
    const int b  = bi / Nc;
    const int i  = bi - b * Nc;
    const int t  = threadIdx.x;

    __shared__ float4 su[NNb];             // unit vec x,y,z + d (A operand)
    __shared__ float  ufa[NNb], sfr[NNb];
    __shared__ v4f  pxy[NNb];              // {x[s],x[s+1],y[s],y[s+1]}
    __shared__ v4f  pzd[NNb];              // {z[s],z[s+1],d[s],d[s+1]}
    __shared__ v2f  pfa[NNb];              // {fa[s],fa[s+1]}
    __shared__ float pr[16][KRc];
    __shared__ float red[4][KAc];

    const int ti = atom_types[i];

    // ---- phase 1: scalar per-neighbor staging ----
    if (t < NNb) {
        const float* cb = coords + (size_t)(b * Nc) * 3;
        int j = t + (t >= i);
        float dx = cb[i*3+0] - cb[j*3+0];
        float dy = cb[i*3+1] - cb[j*3+1];
        float dz = cb[i*3+2] - cb[j*3+2];
        float d2 = dx*dx + dy*dy + dz*dz;
        float d  = __builtin_amdgcn_sqrtf(d2);
        float inv = 1.0f / d;
        su[t]  = make_float4(dx*inv, dy*inv, dz*inv, d);
        ufa[t] = fmaf(cos_rev(d * (0.5f / RCAf)), 0.5f, 0.5f);
        sfr[t] = fmaf(cos_rev(d * (0.5f / RCRf)), 0.5f, 0.5f);
    }

    // ---- fast-path detection from scalar (uniform) loads only ----
    bool fast;
    float ea0, dLs, c10;
    {
        float z0 = Zeta[ti * KAc + 0];
        bool zu = true;
#pragma unroll
        for (int k = 1; k < KAc; ++k) zu = zu && (Zeta[ti * KAc + k] == z0);
        float e0v = EtaA[ti * KAc + 0] * L2E;
        float e1v = EtaA[ti * KAc + 1] * L2E;
        float dv  = e1v - e0v;
        bool ar = true;
#pragma unroll
        for (int k = 2; k < KAc; ++k) {
            float ev = EtaA[ti * KAc + k] * L2E;
            ar = ar && (fabsf(ev - (e0v + dv * (float)k)) <=
                        1e-5f * fabsf(ev) + 1e-7f);
        }
        fast = zu && ar && (z0 == 32.0f);
        ea0 = e0v; dLs = dv; c10 = 1.0f - z0;
    }

    __syncthreads();

    // ---- phase 2: pair-shifted packed SoA for the B operand ----
    if (t < NNb) {
        int s1 = t + 1; if (s1 >= NNb) s1 = 0;
        float4 a = su[t], c = su[s1];
        pxy[t] = (v4f){a.x, c.x, a.y, c.y};
        pzd[t] = (v4f){a.z, c.z, a.w, c.w};
        pfa[t] = (v2f){ufa[t], ufa[s1]};
    }

    // ---- radial G2 (all 256 threads) ----
    {
        const int k = t & 15, g = t >> 4;
        float er  = EtaR[ti * KRc + k];
        float sr  = ShfR[ti * KRc + k];
        float erL = -er * L2E;
        float acc = 0.0f;
        for (int jj = g; jj < NNb; jj += 16) {
            float dd = su[jj].w - sr;
            acc += __builtin_amdgcn_exp2f(erL * dd * dd) * sfr[jj];
        }
        pr[g][k] = acc;
    }
    __syncthreads();

    // ---- angular G3: packed-pair index walk, all threads ----
    float av[KAc];

    if (fast) {
        v2f acc2[KAc];
#pragma unroll
        for (int k = 0; k < KAc; ++k) acc2[k] = sp(0.0f);

        // init (j, rr) from t: slot index p = t, p = rp*95 + j, rr = 2*rp+1
        int j = t, rr = 1;
        if (j >= NNb) { j -= NNb; rr = 3; }
        if (j >= NNb) { j -= NNb; rr = 5; }

#pragma unroll 3
        for (int it = 0; it < 9; ++it) {
            int j2 = j + rr; if (j2 >= NNb) j2 -= NNb;

            float4 A  = su[j];
            float  fa = ufa[j];
            v4f xy = pxy[j2];
            v4f zd = pzd[j2];
            v2f fb = pfa[j2];
            v2f Bx = xy.xy, By = xy.zw;
            v2f Bz = zd.xy, Bw = zd.zw;

            v2f mask;
            mask.x = (rr < 48) ? 1.0f : 0.0f;
            mask.y = (rr < 47) ? 1.0f : 0.0f;

            v2f cosv = pfma(sp(A.x), Bx, pfma(sp(A.y), By, sp(A.z) * Bz));
            v2f sAB  = pfma(Bw, Bw, sp(A.w * A.w));
            v2f d23sq = pmax(pfma(sp(-2.0f * A.w) * Bw, cosv, sAB), sp(0.0f));
            v2f f23 = pfma(pcosr(psqrt(d23sq) * sp(0.5f / RCAf)),
                           sp(0.5f), sp(0.5f));
            v2f fprod = (sp(fa) * fb) * (f23 * mask);
            v2f s  = sAB + d23sq;
            v2f tt = pmax(sp(1.0f) + cosv, sp(0.0f));
            v2f t2 = tt*tt, t4 = t2*t2, t8 = t4*t4, t16 = t8*t8;
            v2f F  = t16 * t16 * fprod;
            v2f e0 = pexp2(pfma(sp(-ea0), s, sp(c10)));
            v2f q  = pexp2(sp(-dLs) * s);
            v2f q2 = q * q;
            v2f e1 = e0*q,  e2 = e0*q2, e3 = e1*q2;
            v2f e4 = e2*q2, e5 = e3*q2, e6 = e4*q2, e7 = e5*q2;
            acc2[0] = pfma(F, e0, acc2[0]);
            acc2[1] = pfma(F, e1, acc2[1]);
            acc2[2] = pfma(F, e2, acc2[2]);
            acc2[3] = pfma(F, e3, acc2[3]);
            acc2[4] = pfma(F, e4, acc2[4]);
            acc2[5] = pfma(F, e5, acc2[5]);
            acc2[6] = pfma(F, e6, acc2[6]);
            acc2[7] = pfma(F, e7, acc2[7]);

            // p += 256  (256 = 2*95 + 66)
            j += 66; rr += 4;
            if (j >= NNb) { j -= NNb; rr += 2; }
        }
#pragma unroll
        for (int k = 0; k < KAc; ++k) av[k] = acc2[k].x + acc2[k].y;
    } else {
        // generic fallback: reload params here (keeps fast path lean)
        float zek[KAc], c1k[KAc], eaL[KAc];
#pragma unroll
        for (int k = 0; k < KAc; ++k) {
            float z = Zeta[ti * KAc + k];
            zek[k] = z;
            c1k[k] = 1.0f - z;
            eaL[k] = EtaA[ti * KAc + k] * L2E;
        }
        float accS[KAc];
#pragma unroll
        for (int k = 0; k < KAc; ++k) accS[k] = 0.0f;

        int j = t, rr = 1;
        if (j >= NNb) { j -= NNb; rr = 3; }
        if (j >= NNb) { j -= NNb; rr = 5; }

        for (int it = 0; it < 9; ++it) {
            float4 A  = su[j];
            float  fa = ufa[j];
            float d2A = A.w * A.w;
#pragma unroll
            for (int half = 0; half < 2; ++half) {
                int rh = rr + half;
                float lv = (rh <= 47) ? 1.0f : 0.0f;
                int j2 = j + rh; if (j2 >= NNb) j2 -= NNb;
                float4 Bq = su[j2];
                float fb = ufa[j2];
                float cosv = fmaf(A.x, Bq.x, fmaf(A.y, Bq.y, A.z * Bq.z));
                float sAB  = fmaf(Bq.w, Bq.w, d2A);
                float d23sq = fmaxf(fmaf(-2.0f * A.w * Bq.w, cosv, sAB), 0.0f);
                float d23 = __builtin_amdgcn_sqrtf(d23sq);
                float f23 = fmaf(cos_rev(d23 * (0.5f / RCAf)), 0.5f, 0.5f);
                float fprod = fa * fb * f23 * lv;
                float s  = sAB + d23sq;
                float tt = fmaxf(1.0f + cosv, 0.0f);
                float l2 = __builtin_amdgcn_logf(tt);   // log2; -inf at 0 ok
#pragma unroll
                for (int k = 0; k < KAc; ++k) {
                    float E = fmaf(zek[k], l2, c1k[k]);
                    E = fmaf(-eaL[k], s, E);
                    accS[k] += __builtin_amdgcn_exp2f(E) * fprod;
                }
            }
            j += 66; rr += 4;
            if (j >= NNb) { j -= NNb; rr += 2; }
        }
#pragma unroll
        for (int k = 0; k < KAc; ++k) av[k] = accS[k];
    }

    // ---- reductions ----
    const int lane = t & 63, wv = t >> 6;
#pragma unroll
    for (int k = 0; k < KAc; ++k) {
        float v = av[k];
#pragma unroll
        for (int off = 32; off; off >>= 1) v += __shfl_xor(v, off, 64);
        if (lane == 0) red[wv][k] = v;
    }
    __syncthreads();

    if (t < KAc) {
        out[bi * NOUT + KRc + t] =
            red[0][t] + red[1][t] + red[2][t] + red[3][t];
    }
    if (t < KRc) {
        float s = 0.0f;
#pragma unroll
        for (int g2 = 0; g2 < 16; ++g2) s += pr[g2][t];
        out[bi * NOUT + t] = s;
    }
}

extern "C" void kernel_launch(void* const* d_in, const int* in_sizes, int n_in,
                              void* d_out, int out_size, void* d_ws, size_t ws_size,
                              hipStream_t stream) {
    const float* coords     = (const float*)d_in[0];
    const int*   atom_types = (const int*)d_in[1];
    const float* EtaR       = (const float*)d_in[2];
    const float* ShfR       = (const float*)d_in[3];
    const float* Zeta       = (const float*)d_in[4];
    const float* EtaA       = (const float*)d_in[5];
    float* out = (float*)d_out;

    ani_feat_kernel<<<dim3(Bc * Nc), dim3(256), 0, stream>>>(
        coords, atom_types, EtaR, ShfR, Zeta, EtaA, out);
}